// Round 1
// baseline (725.388 us; speedup 1.0000x reference)
//
#include <hip/hip_runtime.h>

// LocallyConnected2D: B=16, H=W=64, CIN=32, 3x3 valid, F=64, OR=OC=62.
// R3: the kernel is an HBM weight-streaming problem: weights are 283 MB
// (92% of mandatory traffic, zero reuse, > 256 MB L3). R2 had depth-1
// weight prefetch: ~560 cy of hideable work per iter vs ~900 cy HBM miss
// latency -> per-iter stall (~57% of achievable BW). R3 changes:
//  (a) 3-deep explicit weight prefetch, first 3 loads issued BEFORE the
//      staging barrier so the stream never idles;
//  (b) staging x-loads batched (addresses + 5 independent loads up front,
//      then LDS-transpose writes) instead of a serialized load/write loop;
//  (c) nontemporal weight loads + output stores (single-use data; keep
//      L2/L3 for x, which IS reused across neighboring blocks).
// Everything else (layout, reduction, epilogue) identical to R2.

typedef float f32x4 __attribute__((ext_vector_type(4)));

#define NB 16
#define CIN 32
#define F 64
#define OR 62
#define OC 62
#define KK 288
#define PADT 20       // patchT row stride (floats): 16B-aligned, conflict-free
#define KPW 72        // k-rows per wave
#define WSTEP (4 * F) // floats between consecutive t-step weight rows (1 KB)

__device__ __forceinline__ void fma4(f32x4& a, float s, const f32x4 w) {
    a[0] = fmaf(s, w[0], a[0]);
    a[1] = fmaf(s, w[1], a[1]);
    a[2] = fmaf(s, w[2], a[2]);
    a[3] = fmaf(s, w[3], a[3]);
}

__device__ __forceinline__ f32x4 ntload(const float* p) {
    return __builtin_nontemporal_load(reinterpret_cast<const f32x4*>(p));
}

__global__ __launch_bounds__(256, 4)
void lc2d_kernel(const float* __restrict__ x,
                 const float* __restrict__ kern,
                 const float* __restrict__ bias,
                 float* __restrict__ out) {
    __shared__ __align__(16) float patchT[KK * PADT];   // 23040 B; reused as redtile

    const int p    = blockIdx.x;
    const int orr  = p / OC;
    const int occ  = p - orr * OC;
    const int tid  = threadIdx.x;
    const int lane = tid & 63;
    const int wv   = tid >> 6;      // wave 0..3
    const int q    = lane >> 4;     // quarter 0..3 -> k-row within 4-row group
    const int fq   = lane & 15;     // f4 slot

    // ---- start the weight HBM stream immediately, 3 deep ----
    const float* __restrict__ wp =
        kern + (size_t)p * (KK * F) + (KPW * wv + q) * F + 4 * fq;
    f32x4 w0 = ntload(wp + 0 * WSTEP);
    f32x4 w1 = ntload(wp + 1 * WSTEP);
    f32x4 w2 = ntload(wp + 2 * WSTEP);

    // ---- stage patchT[k][b]: batched loads, then transpose-writes ----
    // idx_m = tid + 256*m; b = idx&15 == tid&15 for all m (256 % 16 == 0).
    const int b_ = tid & 15;
    int krow[5];
    const float* ga[5];
#pragma unroll
    for (int m = 0; m < 5; ++m) {
        const int idx = tid + 256 * m;
        const int k = (idx >> 4) << 2;       // 4-aligned (c 4-aligned too)
        const int i = k / 96;
        const int r = k - i * 96;
        krow[m] = k;
        ga[m] = x + (((b_ * 64 + orr + i) * 64) + (occ + (r >> 5))) * CIN + (r & 31);
    }
    const bool has5 = (tid < 128);           // idx_4 = tid+1024 < 1152
    f32x4 s0 = *reinterpret_cast<const f32x4*>(ga[0]);
    f32x4 s1 = *reinterpret_cast<const f32x4*>(ga[1]);
    f32x4 s2 = *reinterpret_cast<const f32x4*>(ga[2]);
    f32x4 s3 = *reinterpret_cast<const f32x4*>(ga[3]);
    f32x4 s4 = {0.f, 0.f, 0.f, 0.f};
    if (has5) s4 = *reinterpret_cast<const f32x4*>(ga[4]);

    {
        // ds_write banks: 2-way aliasing across the wave -> free (m136)
        float* pt0 = &patchT[krow[0] * PADT + b_];
        pt0[0 * PADT] = s0[0]; pt0[1 * PADT] = s0[1];
        pt0[2 * PADT] = s0[2]; pt0[3 * PADT] = s0[3];
        float* pt1 = &patchT[krow[1] * PADT + b_];
        pt1[0 * PADT] = s1[0]; pt1[1 * PADT] = s1[1];
        pt1[2 * PADT] = s1[2]; pt1[3 * PADT] = s1[3];
        float* pt2 = &patchT[krow[2] * PADT + b_];
        pt2[0 * PADT] = s2[0]; pt2[1 * PADT] = s2[1];
        pt2[2 * PADT] = s2[2]; pt2[3 * PADT] = s2[3];
        float* pt3 = &patchT[krow[3] * PADT + b_];
        pt3[0 * PADT] = s3[0]; pt3[1 * PADT] = s3[1];
        pt3[2 * PADT] = s3[2]; pt3[3 * PADT] = s3[3];
        if (has5) {
            float* pt4 = &patchT[krow[4] * PADT + b_];
            pt4[0 * PADT] = s4[0]; pt4[1 * PADT] = s4[1];
            pt4[2 * PADT] = s4[2]; pt4[3 * PADT] = s4[3];
        }
    }
    __syncthreads();

    // ---- main loop: 18 iters, 1 KB distinct weight bytes per wave-instr ----
    f32x4 acc[16];
#pragma unroll
    for (int u = 0; u < 16; ++u) acc[u] = (f32x4){0.f, 0.f, 0.f, 0.f};

    const float* __restrict__ ptbase = &patchT[(KPW * wv + q) * PADT];

#pragma unroll 6
    for (int t = 0; t < 18; ++t) {
        const f32x4 wcur = w0;
        w0 = w1;
        w1 = w2;
        if (t < 15)
            w2 = ntload(wp + (t + 3) * WSTEP);
        const float* pt = ptbase + t * (4 * PADT);
        const f32x4 p0 = *reinterpret_cast<const f32x4*>(pt + 0);
        const f32x4 p1 = *reinterpret_cast<const f32x4*>(pt + 4);
        const f32x4 p2 = *reinterpret_cast<const f32x4*>(pt + 8);
        const f32x4 p3 = *reinterpret_cast<const f32x4*>(pt + 12);
        fma4(acc[0],  p0[0], wcur); fma4(acc[1],  p0[1], wcur);
        fma4(acc[2],  p0[2], wcur); fma4(acc[3],  p0[3], wcur);
        fma4(acc[4],  p1[0], wcur); fma4(acc[5],  p1[1], wcur);
        fma4(acc[6],  p1[2], wcur); fma4(acc[7],  p1[3], wcur);
        fma4(acc[8],  p2[0], wcur); fma4(acc[9],  p2[1], wcur);
        fma4(acc[10], p2[2], wcur); fma4(acc[11], p2[3], wcur);
        fma4(acc[12], p3[0], wcur); fma4(acc[13], p3[1], wcur);
        fma4(acc[14], p3[2], wcur); fma4(acc[15], p3[3], wcur);
    }

    // ---- intra-wave reduction across quarters (k mod 4 partials) ----
    // step 1 (xor 32): exchange the b-half the partner keeps.
    const bool hi = (q >= 2);       // quarters 2,3 keep b8..15
    f32x4 acck[8];
#pragma unroll
    for (int s = 0; s < 8; ++s) {
        const f32x4 send = hi ? acc[s] : acc[s + 8];
        f32x4 recv;
        recv[0] = __shfl_xor(send[0], 32);
        recv[1] = __shfl_xor(send[1], 32);
        recv[2] = __shfl_xor(send[2], 32);
        recv[3] = __shfl_xor(send[3], 32);
        const f32x4 mine = hi ? acc[s + 8] : acc[s];
        acck[s] = mine + recv;
    }
    // step 2 (xor 16): sum the remaining two k-partials.
#pragma unroll
    for (int s = 0; s < 8; ++s) {
        acck[s][0] += __shfl_xor(acck[s][0], 16);
        acck[s][1] += __shfl_xor(acck[s][1], 16);
        acck[s][2] += __shfl_xor(acck[s][2], 16);
        acck[s][3] += __shfl_xor(acck[s][3], 16);
    }

    // ---- cross-wave reduction via LDS (reuse patchT) ----
    __syncthreads();   // all patchT reads done before overwrite
    {
        const int sbase = (q & 1) * 4;           // which kept slots this quarter writes
        float* red = patchT + wv * 1024 + (4 * q) * F + 4 * fq;  // b = 4q+u
#pragma unroll
        for (int u = 0; u < 4; ++u)
            *reinterpret_cast<f32x4*>(red + u * F) = acck[sbase + u];
    }
    __syncthreads();

    // ---- epilogue: thread t -> (b = t/16, f4 = t%16); sum 4 waves + bias ----
    {
        const int fb = tid >> 4;
        const int ff = tid & 15;
        const float* r0 = patchT + fb * F + 4 * ff;
        const f32x4 s0e = *reinterpret_cast<const f32x4*>(r0 + 0 * 1024);
        const f32x4 s1e = *reinterpret_cast<const f32x4*>(r0 + 1 * 1024);
        const f32x4 s2e = *reinterpret_cast<const f32x4*>(r0 + 2 * 1024);
        const f32x4 s3e = *reinterpret_cast<const f32x4*>(r0 + 3 * 1024);
        const f32x4 bv = *reinterpret_cast<const f32x4*>(bias + p * F + 4 * ff);
        const f32x4 o = s0e + s1e + s2e + s3e + bv;
        float* op = out + ((size_t)fb * (OR * OC) + p) * F + 4 * ff;
        __builtin_nontemporal_store(o, reinterpret_cast<f32x4*>(op));
    }
}

extern "C" void kernel_launch(void* const* d_in, const int* in_sizes, int n_in,
                              void* d_out, int out_size, void* d_ws, size_t ws_size,
                              hipStream_t stream) {
    const float* x    = (const float*)d_in[0];
    const float* kern = (const float*)d_in[1];
    const float* bias = (const float*)d_in[2];
    float* out = (float*)d_out;
    lc2d_kernel<<<dim3(OR * OC), dim3(256), 0, stream>>>(x, kern, bias, out);
}

// Round 2
// 395.992 us; speedup vs baseline: 1.8318x; 1.8318x over previous
//
#include <hip/hip_runtime.h>

// LocallyConnected2D: B=16, H=W=64, CIN=32, 3x3 valid, F=64, OR=OC=62.
// R4: R3 (3-deep prefetch + unroll 6) spilled acc[16] to scratch under the
// 128-VGPR cap of __launch_bounds__(256,4): WRITE_SIZE 1.04 GB (vs 16 MB
// output), FETCH +350 MB of scratch re-reads, kernel 84 -> 435 us. R4 keeps
// R3's good parts (weight stream started before staging; batched staging
// loads; nontemporal on the zero-reuse 283 MB weight stream) but restores
// register discipline: depth-2 prefetch ring (12 w-VGPRs) + unroll 2.
// Live set ~= acc 64 + patches 16 + w 12 + misc ~20 = ~112 <= 128 cap.
// Depth-2 covers HBM latency: issue at t, use at t+2 ~= 1120 cy > ~900 cy.

typedef float f32x4 __attribute__((ext_vector_type(4)));

#define NB 16
#define CIN 32
#define F 64
#define OR 62
#define OC 62
#define KK 288
#define PADT 20       // patchT row stride (floats): 16B-aligned, conflict-free
#define KPW 72        // k-rows per wave
#define WSTEP (4 * F) // floats between consecutive t-step weight rows (1 KB)

__device__ __forceinline__ void fma4(f32x4& a, float s, const f32x4 w) {
    a[0] = fmaf(s, w[0], a[0]);
    a[1] = fmaf(s, w[1], a[1]);
    a[2] = fmaf(s, w[2], a[2]);
    a[3] = fmaf(s, w[3], a[3]);
}

__device__ __forceinline__ f32x4 ntload(const float* p) {
    return __builtin_nontemporal_load(reinterpret_cast<const f32x4*>(p));
}

__global__ __launch_bounds__(256, 4)
void lc2d_kernel(const float* __restrict__ x,
                 const float* __restrict__ kern,
                 const float* __restrict__ bias,
                 float* __restrict__ out) {
    __shared__ __align__(16) float patchT[KK * PADT];   // 23040 B; reused as redtile

    const int p    = blockIdx.x;
    const int orr  = p / OC;
    const int occ  = p - orr * OC;
    const int tid  = threadIdx.x;
    const int lane = tid & 63;
    const int wv   = tid >> 6;      // wave 0..3
    const int q    = lane >> 4;     // quarter 0..3 -> k-row within 4-row group
    const int fq   = lane & 15;     // f4 slot

    // ---- start the weight HBM stream immediately, depth 2 ----
    const float* __restrict__ wp =
        kern + (size_t)p * (KK * F) + (KPW * wv + q) * F + 4 * fq;
    f32x4 w0 = ntload(wp + 0 * WSTEP);
    f32x4 w1 = ntload(wp + 1 * WSTEP);

    // ---- stage patchT[k][b]: batched loads, then transpose-writes ----
    // idx_m = tid + 256*m; b = idx&15 == tid&15 for all m (256 % 16 == 0).
    const int b_ = tid & 15;
    int krow[5];
    const float* ga[5];
#pragma unroll
    for (int m = 0; m < 5; ++m) {
        const int idx = tid + 256 * m;
        const int k = (idx >> 4) << 2;       // 4-aligned (c 4-aligned too)
        const int i = k / 96;
        const int r = k - i * 96;
        krow[m] = k;
        ga[m] = x + (((b_ * 64 + orr + i) * 64) + (occ + (r >> 5))) * CIN + (r & 31);
    }
    const bool has5 = (tid < 128);           // idx_4 = tid+1024 < 1152
    f32x4 s0 = *reinterpret_cast<const f32x4*>(ga[0]);
    f32x4 s1 = *reinterpret_cast<const f32x4*>(ga[1]);
    f32x4 s2 = *reinterpret_cast<const f32x4*>(ga[2]);
    f32x4 s3 = *reinterpret_cast<const f32x4*>(ga[3]);
    f32x4 s4 = {0.f, 0.f, 0.f, 0.f};
    if (has5) s4 = *reinterpret_cast<const f32x4*>(ga[4]);

    {
        // ds_write banks: 2-way aliasing across the wave -> free (m136)
        float* pt0 = &patchT[krow[0] * PADT + b_];
        pt0[0 * PADT] = s0[0]; pt0[1 * PADT] = s0[1];
        pt0[2 * PADT] = s0[2]; pt0[3 * PADT] = s0[3];
        float* pt1 = &patchT[krow[1] * PADT + b_];
        pt1[0 * PADT] = s1[0]; pt1[1 * PADT] = s1[1];
        pt1[2 * PADT] = s1[2]; pt1[3 * PADT] = s1[3];
        float* pt2 = &patchT[krow[2] * PADT + b_];
        pt2[0 * PADT] = s2[0]; pt2[1 * PADT] = s2[1];
        pt2[2 * PADT] = s2[2]; pt2[3 * PADT] = s2[3];
        float* pt3 = &patchT[krow[3] * PADT + b_];
        pt3[0 * PADT] = s3[0]; pt3[1 * PADT] = s3[1];
        pt3[2 * PADT] = s3[2]; pt3[3 * PADT] = s3[3];
        if (has5) {
            float* pt4 = &patchT[krow[4] * PADT + b_];
            pt4[0 * PADT] = s4[0]; pt4[1 * PADT] = s4[1];
            pt4[2 * PADT] = s4[2]; pt4[3 * PADT] = s4[3];
        }
    }
    __syncthreads();

    // ---- main loop: 18 iters, 1 KB distinct weight bytes per wave-instr ----
    f32x4 acc[16];
#pragma unroll
    for (int u = 0; u < 16; ++u) acc[u] = (f32x4){0.f, 0.f, 0.f, 0.f};

    const float* __restrict__ ptbase = &patchT[(KPW * wv + q) * PADT];

#pragma unroll 2
    for (int t = 0; t < 18; ++t) {
        const f32x4 wcur = w0;
        w0 = w1;
        if (t < 16)
            w1 = ntload(wp + (t + 2) * WSTEP);
        const float* pt = ptbase + t * (4 * PADT);
        const f32x4 p0 = *reinterpret_cast<const f32x4*>(pt + 0);
        const f32x4 p1 = *reinterpret_cast<const f32x4*>(pt + 4);
        const f32x4 p2 = *reinterpret_cast<const f32x4*>(pt + 8);
        const f32x4 p3 = *reinterpret_cast<const f32x4*>(pt + 12);
        fma4(acc[0],  p0[0], wcur); fma4(acc[1],  p0[1], wcur);
        fma4(acc[2],  p0[2], wcur); fma4(acc[3],  p0[3], wcur);
        fma4(acc[4],  p1[0], wcur); fma4(acc[5],  p1[1], wcur);
        fma4(acc[6],  p1[2], wcur); fma4(acc[7],  p1[3], wcur);
        fma4(acc[8],  p2[0], wcur); fma4(acc[9],  p2[1], wcur);
        fma4(acc[10], p2[2], wcur); fma4(acc[11], p2[3], wcur);
        fma4(acc[12], p3[0], wcur); fma4(acc[13], p3[1], wcur);
        fma4(acc[14], p3[2], wcur); fma4(acc[15], p3[3], wcur);
    }

    // ---- intra-wave reduction across quarters (k mod 4 partials) ----
    // step 1 (xor 32): exchange the b-half the partner keeps.
    const bool hi = (q >= 2);       // quarters 2,3 keep b8..15
    f32x4 acck[8];
#pragma unroll
    for (int s = 0; s < 8; ++s) {
        const f32x4 send = hi ? acc[s] : acc[s + 8];
        f32x4 recv;
        recv[0] = __shfl_xor(send[0], 32);
        recv[1] = __shfl_xor(send[1], 32);
        recv[2] = __shfl_xor(send[2], 32);
        recv[3] = __shfl_xor(send[3], 32);
        const f32x4 mine = hi ? acc[s + 8] : acc[s];
        acck[s] = mine + recv;
    }
    // step 2 (xor 16): sum the remaining two k-partials.
#pragma unroll
    for (int s = 0; s < 8; ++s) {
        acck[s][0] += __shfl_xor(acck[s][0], 16);
        acck[s][1] += __shfl_xor(acck[s][1], 16);
        acck[s][2] += __shfl_xor(acck[s][2], 16);
        acck[s][3] += __shfl_xor(acck[s][3], 16);
    }

    // ---- cross-wave reduction via LDS (reuse patchT) ----
    __syncthreads();   // all patchT reads done before overwrite
    {
        const int sbase = (q & 1) * 4;           // which kept slots this quarter writes
        float* red = patchT + wv * 1024 + (4 * q) * F + 4 * fq;  // b = 4q+u
#pragma unroll
        for (int u = 0; u < 4; ++u)
            *reinterpret_cast<f32x4*>(red + u * F) = acck[sbase + u];
    }
    __syncthreads();

    // ---- epilogue: thread t -> (b = t/16, f4 = t%16); sum 4 waves + bias ----
    {
        const int fb = tid >> 4;
        const int ff = tid & 15;
        const float* r0 = patchT + fb * F + 4 * ff;
        const f32x4 s0e = *reinterpret_cast<const f32x4*>(r0 + 0 * 1024);
        const f32x4 s1e = *reinterpret_cast<const f32x4*>(r0 + 1 * 1024);
        const f32x4 s2e = *reinterpret_cast<const f32x4*>(r0 + 2 * 1024);
        const f32x4 s3e = *reinterpret_cast<const f32x4*>(r0 + 3 * 1024);
        const f32x4 bv = *reinterpret_cast<const f32x4*>(bias + p * F + 4 * ff);
        const f32x4 o = s0e + s1e + s2e + s3e + bv;
        float* op = out + ((size_t)fb * (OR * OC) + p) * F + 4 * ff;
        __builtin_nontemporal_store(o, reinterpret_cast<f32x4*>(op));
    }
}

extern "C" void kernel_launch(void* const* d_in, const int* in_sizes, int n_in,
                              void* d_out, int out_size, void* d_ws, size_t ws_size,
                              hipStream_t stream) {
    const float* x    = (const float*)d_in[0];
    const float* kern = (const float*)d_in[1];
    const float* bias = (const float*)d_in[2];
    float* out = (float*)d_out;
    lc2d_kernel<<<dim3(OR * OC), dim3(256), 0, stream>>>(x, kern, bias, out);
}